// Round 3
// baseline (101.386 us; speedup 1.0000x reference)
//
#include <hip/hip_runtime.h>

// ALNN layer: B=64, K=13, L=200, D=64, fp32. Two-stage, latency-fixed.
//
// Stage 1: block = (l-chunk of 2) x (batch-group of 8); threads split k.
//   256 threads = dq(16) x b(8) x kslot(2); kslot 0 -> k 0..6, 1 -> k 7..12.
//   acc[7] float4 per thread (28 VGPR) -- no 13-wide unroll, no spill.
//   Inputs read once from HBM/L2 (12.5 MB); weights once per batch-group
//   (8x = 32 MB); partials [NC][B][K][ND4] = 21.3 MB to d_ws.
// Stage 2: 4 threads per output float4 (25 chunks each) + 2 shfl_xor folds.
//   Thread layout g = bk*64 + q*16 + dq -> needs NB*NK*64 threads = 208
//   blocks (ROUND-2 BUG: launched 832 -> OOB writes on out[]; fixed, plus
//   defensive bk guard). Deterministic, no atomics.

#define NB 64
#define NK 13
#define NL 200
#define ND 64
#define ND4 16        // float4s per d-row
#define GB 8          // batches per block
#define LC 2          // l per chunk
#define NC (NL / LC)  // 100 chunks

__global__ __launch_bounds__(256) void alnn_stage1(
    const float* __restrict__ X, const float* __restrict__ T,
    const float* __restrict__ M, const float* __restrict__ DT,
    const float* __restrict__ alpha, const float* __restrict__ w_v,
    const float* __restrict__ w_t, const float* __restrict__ b_t,
    float4* __restrict__ part)
{
    // Grid 832 = 8 xcd-slots x 8 bg x 13 chi. bid%8 == c%8 so the 8 blocks
    // sharing one chunk's weight slice land on one XCD's L2 (round-robin
    // dispatch heuristic; perf-only).
    const int bid = blockIdx.x;
    const int clo = bid & 7;
    const int g   = bid >> 3;          // 0..103
    const int bg  = g & 7;
    const int chi = g >> 3;            // 0..12
    const int c   = chi * 8 + clo;     // 0..103
    if (c >= NC) return;

    const int tid = threadIdx.x;
    const int dq  = tid & 15;          // float4 index along d
    const int b8  = (tid >> 4) & 7;    // batch within group
    const int ks  = tid >> 7;          // k-slot: 0 or 1
    const int k0  = ks * 7;            // k 0..6 / 7..12
    const int b   = (bg << 3) + b8;
    const int la  = c * LC;

    const float4* X4  = (const float4*)X;
    const float4* T4  = (const float4*)T;
    const float4* M4  = (const float4*)M;
    const float4* DT4 = (const float4*)DT;
    const float4* WT4 = (const float4*)w_t;   // f4 idx = (k*NL+l)*ND + d
    const float4* BT4 = (const float4*)b_t;   // f4 idx = (k*NL+l)*ND4 + dq
    const float4* WV4 = (const float4*)w_v;

    // hoisted per-k constants (static-indexed, stays in registers)
    float av[7], rv[7];
    #pragma unroll
    for (int i = 0; i < 7; ++i) {
        const int k = k0 + i;
        av[i] = (k < NK) ? fmaxf(alpha[k], 0.f) : 0.f;
        rv[i] = 4.f * (float)k;        // linspace(0,48,13) step = 4
    }

    float4 acc[7];
    #pragma unroll
    for (int i = 0; i < 7; ++i) acc[i] = make_float4(0.f, 0.f, 0.f, 0.f);

#define COMP(c_, wt, A) {                                                 \
        const float dist  = fabsf(t4.c_ - reft);                          \
        const float inten = fmaxf(x4.c_ * __expf(-a * dist), 0.f);        \
        const float sf = wt.x * x4.c_ + wt.y * dt4.c_ + wt.z * inten +    \
                         wt.w * m4.c_ + 4.f * bt4.c_;                     \
        A.c_ = fmaf(wv4.c_, fmaxf(sf, 0.f), A.c_);                        \
    }

    #pragma unroll
    for (int li = 0; li < LC; ++li) {
        const int l  = la + li;
        const int io = (b * NL + l) * ND4 + dq;
        const float4 x4  = X4[io];
        const float4 t4  = T4[io];
        const float4 m4  = M4[io];
        const float4 dt4 = DT4[io];
        #pragma unroll
        for (int i = 0; i < 7; ++i) {
            const int k = k0 + i;
            if (k < NK) {
                const int w0 = (k * NL + l) * ND + (dq << 2);
                const float4 wt0 = WT4[w0 + 0];
                const float4 wt1 = WT4[w0 + 1];
                const float4 wt2 = WT4[w0 + 2];
                const float4 wt3 = WT4[w0 + 3];
                const int   wq  = (k * NL + l) * ND4 + dq;
                const float4 bt4 = BT4[wq];
                const float4 wv4 = WV4[wq];
                const float a    = av[i];
                const float reft = rv[i];
                COMP(x, wt0, acc[i])
                COMP(y, wt1, acc[i])
                COMP(z, wt2, acc[i])
                COMP(w, wt3, acc[i])
            }
        }
    }
#undef COMP

    // each (c,b,k,dq) partial owned by exactly one thread: plain store,
    // lanes dq consecutive -> 256B coalesced per (c,b,k) row
    const int pb = ((c * NB + b) * NK + k0) * ND4 + dq;
    #pragma unroll
    for (int i = 0; i < 7; ++i)
        if (k0 + i < NK) part[pb + i * ND4] = acc[i];
}

__global__ __launch_bounds__(256) void alnn_stage2(
    const float4* __restrict__ part, const float* __restrict__ b_v,
    float4* __restrict__ out)
{
    // 4 threads per output float4, each reduces 25 of the 100 chunks.
    // g = bk*64 + q*16 + dq  ->  one wave = one bk, q in 0..3, dq in 0..15.
    // Total threads = NB*NK*64 = 53248 -> exactly 208 blocks of 256.
    const int g  = blockIdx.x * 256 + threadIdx.x;   // 0..53247
    const int dq = g & 15;
    const int r  = g >> 4;
    const int q  = r & 3;
    const int bk = r >> 2;                           // b*NK + k, 0..831
    if (bk >= NB * NK) return;                       // defensive

    float4 s = make_float4(0.f, 0.f, 0.f, 0.f);
    #pragma unroll 5
    for (int i = 0; i < NC / 4; ++i) {
        const int c = q * (NC / 4) + i;
        const float4 p = part[(c * NB * NK + bk) * ND4 + dq];
        s.x += p.x; s.y += p.y; s.z += p.z; s.w += p.w;
    }
    // fold the 4 q-partials (same wave: lanes differ in bits 4..5)
    s.x += __shfl_xor(s.x, 16); s.y += __shfl_xor(s.y, 16);
    s.z += __shfl_xor(s.z, 16); s.w += __shfl_xor(s.w, 16);
    s.x += __shfl_xor(s.x, 32); s.y += __shfl_xor(s.y, 32);
    s.z += __shfl_xor(s.z, 32); s.w += __shfl_xor(s.w, 32);

    if (q == 0) {
        const int k = bk % NK;
        const float4 bv = ((const float4*)b_v)[k * ND4 + dq];
        float4 o;
        o.x = fmaxf(s.x + 200.f * bv.x, 0.f);
        o.y = fmaxf(s.y + 200.f * bv.y, 0.f);
        o.z = fmaxf(s.z + 200.f * bv.z, 0.f);
        o.w = fmaxf(s.w + 200.f * bv.w, 0.f);
        out[bk * ND4 + dq] = o;
    }
}

extern "C" void kernel_launch(void* const* d_in, const int* in_sizes, int n_in,
                              void* d_out, int out_size, void* d_ws, size_t ws_size,
                              hipStream_t stream) {
    const float* X     = (const float*)d_in[0];
    const float* T     = (const float*)d_in[1];
    const float* M     = (const float*)d_in[2];
    const float* DT    = (const float*)d_in[3];
    const float* alpha = (const float*)d_in[4];
    const float* w_v   = (const float*)d_in[5];
    const float* w_t   = (const float*)d_in[6];
    const float* b_v   = (const float*)d_in[7];
    const float* b_t   = (const float*)d_in[8];

    float4* part = (float4*)d_ws;    // needs 21.3 MB; ws is 256 MiB

    alnn_stage1<<<832, 256, 0, stream>>>(X, T, M, DT, alpha, w_v, w_t, b_t, part);
    alnn_stage2<<<(NB * NK * 64) / 256, 256, 0, stream>>>(part, b_v, (float4*)d_out);
}